// Round 10
// baseline (194.401 us; speedup 1.0000x reference)
//
#include <hip/hip_runtime.h>
#include <hip/hip_bf16.h>
#include <stdint.h>
#include <stddef.h>

typedef __bf16 bf16_t;
typedef __bf16 bf16x4 __attribute__((ext_vector_type(4)));
typedef __bf16 bf16x8 __attribute__((ext_vector_type(8)));
typedef float f32x4 __attribute__((ext_vector_type(4)));

#define MFMA16(a, b, c) __builtin_amdgcn_mfma_f32_16x16x32_bf16(a, b, c, 0, 0, 0)

// async global->LDS, 16 B per lane; LDS dest = uniform base + lane*16
#define GLL16(g, l)                                                      \
    __builtin_amdgcn_global_load_lds(                                    \
        (const __attribute__((address_space(1))) void*)(g),              \
        (__attribute__((address_space(3))) void*)(l), 16, 0, 0)

#define SEQ 2048
#define NHEAD 16
#define HD 64
#define HID 1024
#define QKV_LD 3072
#define VT_LD 2080  // 2048 + 32 pad: breaks 4 KB power-of-2 L2 set aliasing

// ---------------------------------------------------------------------------
// Fused prep: cast x -> bf16 (blocks 0..4095), transpose+cast w_qkv
// (4096..7167), transpose+cast w_out (7168..8191).
// ---------------------------------------------------------------------------
__global__ __launch_bounds__(256)
void prep_kernel(const float* __restrict__ x, const float* __restrict__ w_qkv,
                 const float* __restrict__ w_out, bf16_t* __restrict__ xbf,
                 bf16_t* __restrict__ wqkvT, bf16_t* __restrict__ woutT) {
    int L = blockIdx.x;
    int tid = threadIdx.x;
    if (L < 4096) {  // cast x
        int i = (L * 256 + tid) * 4;
        float4 v = *(const float4*)(x + i);
        bf16x4 o = {(bf16_t)v.x, (bf16_t)v.y, (bf16_t)v.z, (bf16_t)v.w};
        *(bf16x4*)(xbf + i) = o;
        return;
    }
    __shared__ bf16_t tile[32][33];
    const float* W;
    bf16_t* Wt;
    int N, bx, by;
    if (L < 7168) {
        int r = L - 4096;
        W = w_qkv; Wt = wqkvT; N = 3072; bx = r % 96; by = r / 96;
    } else {
        int r = L - 7168;
        W = w_out; Wt = woutT; N = 1024; bx = r % 32; by = r / 32;
    }
    int K = 1024;
    int n0 = bx * 32, k0 = by * 32;
    int tx = tid & 31, ty = tid >> 5;  // 32 x 8
#pragma unroll
    for (int i = 0; i < 4; i++)
        tile[ty + i * 8][tx] = (bf16_t)W[(size_t)(k0 + ty + i * 8) * N + n0 + tx];
    __syncthreads();
#pragma unroll
    for (int i = 0; i < 4; i++)
        Wt[(size_t)(n0 + ty + i * 8) * K + k0 + tx] = tile[tx][ty + i * 8];
}

// ---------------------------------------------------------------------------
// V transpose prepass: Vt[bh][d][s] = qkv[b][s][2048 + h*64 + d].
// ---------------------------------------------------------------------------
__global__ __launch_bounds__(256)
void vt_transpose(const bf16_t* __restrict__ qkv, bf16_t* __restrict__ Vt) {
    int s0 = blockIdx.x * 64;
    int bh = blockIdx.y;
    int b = bh >> 4, h = bh & 15;
    int tid = threadIdx.x;
    __shared__ __align__(16) bf16_t tile[64][72];

    int row = tid >> 3, c8 = (tid & 7) * 8;
#pragma unroll
    for (int it = 0; it < 2; it++) {
        int sr = row + it * 32;
        bf16x8 v = *(const bf16x8*)(qkv + ((size_t)b * SEQ + s0 + sr) * QKV_LD +
                                    2 * HID + h * HD + c8);
        *(bf16x8*)(&tile[sr][c8]) = v;
    }
    __syncthreads();
#pragma unroll
    for (int it = 0; it < 2; it++) {
        int d = row + it * 32;
        bf16x8 w;
#pragma unroll
        for (int e = 0; e < 8; e++) w[e] = tile[c8 + e][d];
        *(bf16x8*)(Vt + ((size_t)bh * HD + d) * VT_LD + s0 + c8) = w;
    }
}

// ---------------------------------------------------------------------------
// GEMM: C[M][N] = A[M][K] @ Bt[N][K]^T + bias[N].  bf16, fp32 accum, OutT out.
// 128xTN tile, BK=32, 256 thr, GLL width-16 staging into unpadded LDS.
// ---------------------------------------------------------------------------
template <typename OutT, int TN>
__global__ __launch_bounds__(256)
void gemm_bt_bias(const bf16_t* __restrict__ A, const bf16_t* __restrict__ Bt,
                  const float* __restrict__ bias, OutT* __restrict__ C,
                  int M, int N, int K) {
    constexpr int NT = TN / 32;  // acc n-tiles per wave
    __shared__ __align__(16) bf16_t As[128][32];
    __shared__ __align__(16) bf16_t Bs[TN][32];

    int m0 = blockIdx.y * 128;
    int n0 = blockIdx.x * TN;
    int tid = threadIdx.x;
    int wave = tid >> 6, lane = tid & 63;
    int quad = lane >> 4, l16 = lane & 15;
    int wm = (wave >> 1) * 64, wn = (wave & 1) * (TN / 2);

    f32x4 acc[4][NT] = {};

    const bf16_t* a_base =
        A + (size_t)(m0 + wave * 32 + (lane >> 2)) * K + (lane & 3) * 8;
    const bf16_t* b_base =
        Bt + (size_t)(n0 + wave * (TN / 4) + (lane >> 2)) * K + (lane & 3) * 8;
    bf16_t* as_base = &As[wave * 32][0];
    bf16_t* bs_base = &Bs[wave * (TN / 4)][0];

    for (int k0 = 0; k0 < K; k0 += 32) {
        GLL16(a_base + k0, as_base);
        GLL16(a_base + 16 * K + k0, as_base + 16 * 32);
        GLL16(b_base + k0, bs_base);
        if (TN == 128) GLL16(b_base + 16 * K + k0, bs_base + 16 * 32);
        __syncthreads();

        bf16x8 af[4], bfr[NT];
#pragma unroll
        for (int t = 0; t < 4; t++)
            af[t] = *(const bf16x8*)(&As[wm + t * 16 + l16][quad * 8]);
#pragma unroll
        for (int t = 0; t < NT; t++)
            bfr[t] = *(const bf16x8*)(&Bs[wn + t * 16 + l16][quad * 8]);
#pragma unroll
        for (int mt = 0; mt < 4; mt++)
#pragma unroll
            for (int nt = 0; nt < NT; nt++)
                acc[mt][nt] = MFMA16(af[mt], bfr[nt], acc[mt][nt]);
        __syncthreads();
    }

#pragma unroll
    for (int mt = 0; mt < 4; mt++) {
        int row = m0 + wm + mt * 16 + quad * 4;
#pragma unroll
        for (int nt = 0; nt < NT; nt++) {
            int col = n0 + wn + nt * 16 + l16;
            float bv = bias[col];
#pragma unroll
            for (int r = 0; r < 4; r++)
                C[(size_t)(row + r) * N + col] = (OutT)(acc[mt][nt][r] + bv);
        }
    }
}

// ---------------------------------------------------------------------------
// Attention, mask j >= i.  TI=128: wave owns 32 query rows (2 groups of 16);
// staged K/V fragments are SHARED across groups (halves LDS read traffic per
// unit work).  QK^T computed TRANSPOSED (S^T = K.Q^T, operand swap): each
// lane then holds fixed query row i=l16 with 4 consecutive j per quad-reg ->
// P packs into ds_write_b64 (vs 32 scalar b16), and row sums are per-lane
// scalar adds (ones-MFMA deleted; 2-shuffle reduce in epilogue).
// Grid 512 1-D: blocks c and c+256 carry tiles (t, 15-t) -> 17 iters per CU.
// XCD pinning preserved (L%8 == bh%8).  Register prefetch as before.
// ---------------------------------------------------------------------------
__global__ __launch_bounds__(256)
void attn_kernel(const bf16_t* __restrict__ qkv, const bf16_t* __restrict__ Vt,
                 bf16_t* __restrict__ attn_out) {
    int L = blockIdx.x;
    int half = L >> 8, r5 = L & 255;
    int bh = r5 & 31;
    int tile = half ? (15 - (r5 >> 5)) : (r5 >> 5);
    int b = bh >> 4, h = bh & 15;

    int tid = threadIdx.x, wave = tid >> 6, lane = tid & 63;
    int quad = lane >> 4, l16 = lane & 15;

    const bf16_t* q_g = qkv + (size_t)b * SEQ * QKV_LD + (size_t)h * HD;
    const bf16_t* k_g = q_g + HID;
    const bf16_t* vt_g = Vt + (size_t)bh * HD * VT_LD;

    __shared__ __align__(16) bf16_t Ks[128][72];     // K tile [j][d]
    __shared__ __align__(16) bf16_t Vs[64][136];     // V^T tile [d][j]
    __shared__ __align__(16) bf16_t Ps[4][32][136];  // wave-private P [i][j]

    int krow = tid >> 3, kc8 = (tid & 7) * 8;    // K staging: 32 rows/pass
    int vrow = tid >> 4, vc8 = (tid & 15) * 8;   // V staging: 16 rows/pass
    const float QS = 0.125f * 1.44269504088896f; // /sqrt(64) * log2(e)

    int i0 = tile * 128;
    int iwb = i0 + wave * 32;  // wave's 32 query rows

    // Q fragments for both groups, pre-scaled so P = exp2(s) directly.
    // (B-operand mapping == A-operand mapping: k = quad*8+e, n/m = l16.)
    bf16x8 qa[2][2];
#pragma unroll
    for (int g = 0; g < 2; g++) {
        const bf16_t* qrow = q_g + (size_t)(iwb + g * 16 + l16) * QKV_LD;
        bf16x8 t0 = *(const bf16x8*)(qrow + quad * 8);
        bf16x8 t1 = *(const bf16x8*)(qrow + 32 + quad * 8);
#pragma unroll
        for (int e = 0; e < 8; e++) {
            qa[g][0][e] = (bf16_t)((float)t0[e] * QS);
            qa[g][1][e] = (bf16_t)((float)t1[e] * QS);
        }
    }

    f32x4 o[2][4] = {};
    float lsum[2] = {0.0f, 0.0f};

    int jstart = i0;  // tile*128: first iteration is the diagonal block

    // --- preload first K/V tile into registers ---
    bf16x8 kr[4], vr[4];
#pragma unroll
    for (int t = 0; t < 4; t++) {
        kr[t] = *(const bf16x8*)(k_g + (size_t)(jstart + krow + t * 32) * QKV_LD + kc8);
        vr[t] = *(const bf16x8*)(vt_g + (size_t)(vrow + t * 16) * VT_LD + jstart + vc8);
    }

    for (int j0 = jstart; j0 < SEQ; j0 += 128) {
        __syncthreads();  // prev iteration's Ks/Vs readers done
#pragma unroll
        for (int t = 0; t < 4; t++) {
            *(bf16x8*)(&Ks[krow + t * 32][kc8]) = kr[t];
            *(bf16x8*)(&Vs[vrow + t * 16][vc8]) = vr[t];
        }
        __syncthreads();

        // --- issue next tile's loads; they land during compute below ---
        if (j0 + 128 < SEQ) {
#pragma unroll
            for (int t = 0; t < 4; t++) {
                kr[t] = *(const bf16x8*)(k_g + (size_t)(j0 + 128 + krow + t * 32) * QKV_LD + kc8);
                vr[t] = *(const bf16x8*)(vt_g + (size_t)(vrow + t * 16) * VT_LD + j0 + 128 + vc8);
            }
        }

        // --- S^T = K.Q^T: K-frags read ONCE, used by both i-groups ---
        f32x4 s[2][8];
#pragma unroll
        for (int jt = 0; jt < 8; jt++) {
            bf16x8 kb0 = *(const bf16x8*)(&Ks[jt * 16 + l16][quad * 8]);
            bf16x8 kb1 = *(const bf16x8*)(&Ks[jt * 16 + l16][32 + quad * 8]);
#pragma unroll
            for (int g = 0; g < 2; g++) {
                f32x4 a = {};
                a = MFMA16(kb0, qa[g][0], a);
                a = MFMA16(kb1, qa[g][1], a);
                s[g][jt] = a;  // lane: i = l16 (fixed), j = jt*16 + quad*4 + r
            }
        }

        // --- P = exp2(s); b64-packed writes; per-lane row-sum accumulation ---
        if (j0 == jstart) {
#pragma unroll
            for (int g = 0; g < 2; g++) {
                int gi = iwb + g * 16 + l16;
#pragma unroll
                for (int jt = 0; jt < 8; jt++) {
                    bf16x4 pk;
#pragma unroll
                    for (int r = 0; r < 4; r++) {
                        int gj = j0 + jt * 16 + quad * 4 + r;
                        float p = (gj >= gi) ? __builtin_amdgcn_exp2f(s[g][jt][r]) : 0.0f;
                        lsum[g] += p;
                        pk[r] = (bf16_t)p;
                    }
                    *(bf16x4*)(&Ps[wave][g * 16 + l16][jt * 16 + quad * 4]) = pk;
                }
            }
        } else {
#pragma unroll
            for (int g = 0; g < 2; g++) {
#pragma unroll
                for (int jt = 0; jt < 8; jt++) {
                    bf16x4 pk;
#pragma unroll
                    for (int r = 0; r < 4; r++) {
                        float p = __builtin_amdgcn_exp2f(s[g][jt][r]);
                        lsum[g] += p;
                        pk[r] = (bf16_t)p;
                    }
                    *(bf16x4*)(&Ps[wave][g * 16 + l16][jt * 16 + quad * 4]) = pk;
                }
            }
        }

        // --- PV: V^T frags read ONCE, used by both i-groups ---
        bf16x8 pa[2][4];
#pragma unroll
        for (int g = 0; g < 2; g++)
#pragma unroll
            for (int kk = 0; kk < 4; kk++)
                pa[g][kk] = *(const bf16x8*)(&Ps[wave][g * 16 + l16][kk * 32 + quad * 8]);

#pragma unroll
        for (int nt = 0; nt < 4; nt++) {
#pragma unroll
            for (int kk = 0; kk < 4; kk++) {
                bf16x8 vb = *(const bf16x8*)(&Vs[nt * 16 + l16][kk * 32 + quad * 8]);
#pragma unroll
                for (int g = 0; g < 2; g++)
                    o[g][nt] = MFMA16(pa[g][kk], vb, o[g][nt]);
            }
        }
    }

    // --- epilogue: cross-quad row-sum reduce, divide, write ---
#pragma unroll
    for (int g = 0; g < 2; g++) {
        lsum[g] += __shfl_xor(lsum[g], 16, 64);
        lsum[g] += __shfl_xor(lsum[g], 32, 64);  // every lane: rowsum of its l16
    }
#pragma unroll
    for (int g = 0; g < 2; g++) {
#pragma unroll
        for (int r = 0; r < 4; r++) {
            float rs = __shfl(lsum[g], quad * 4 + r, 64);  // rowsum of row quad*4+r
            float inv = 1.0f / rs;
            int gi = iwb + g * 16 + quad * 4 + r;
#pragma unroll
            for (int nt = 0; nt < 4; nt++)
                attn_out[(size_t)(b * SEQ + gi) * HID + h * HD + nt * 16 + l16] =
                    (bf16_t)(o[g][nt][r] * inv);
        }
    }
}

// ---------------------------------------------------------------------------
extern "C" void kernel_launch(void* const* d_in, const int* in_sizes, int n_in,
                              void* d_out, int out_size, void* d_ws, size_t ws_size,
                              hipStream_t stream) {
    const float* x     = (const float*)d_in[0];
    const float* w_qkv = (const float*)d_in[1];
    const float* b_qkv = (const float*)d_in[2];
    const float* w_out = (const float*)d_in[3];
    const float* b_out = (const float*)d_in[4];
    float* out = (float*)d_out;

    char* ws = (char*)d_ws;
    bf16_t* xbf   = (bf16_t*)(ws);               // 8.39 MB; dead after QKV GEMM
    bf16_t* Vt    = (bf16_t*)(ws);               // 8.52 MB; overruns into wqkvT
                                                 // (dead by vt_transpose time)
    bf16_t* wqkvT = (bf16_t*)(ws + 8388608);     // 6.29 MB
    bf16_t* woutT = (bf16_t*)(ws + 14680064);    // 2.10 MB (never overwritten)
    bf16_t* qkv   = (bf16_t*)(ws + 16777216);    // 25.17 MB
    bf16_t* attn  = (bf16_t*)(ws + 41943040);    // 8.39 MB

    prep_kernel<<<8192, 256, 0, stream>>>(x, w_qkv, w_out, xbf, wqkvT, woutT);

    gemm_bt_bias<bf16_t, 128><<<dim3(3072 / 128, 4096 / 128), 256, 0, stream>>>(
        xbf, wqkvT, b_qkv, qkv, 4096, 3072, 1024);

    vt_transpose<<<dim3(SEQ / 64, 2 * NHEAD), 256, 0, stream>>>(qkv, Vt);

    attn_kernel<<<512, 256, 0, stream>>>(qkv, Vt, attn);

    gemm_bt_bias<float, 64><<<dim3(1024 / 64, 4096 / 128), 256, 0, stream>>>(
        attn, woutT, b_out, out, 4096, 1024, 1024);
}

// Round 11
// 182.110 us; speedup vs baseline: 1.0675x; 1.0675x over previous
//
#include <hip/hip_runtime.h>
#include <hip/hip_bf16.h>
#include <stdint.h>
#include <stddef.h>

typedef __bf16 bf16_t;
typedef __bf16 bf16x4 __attribute__((ext_vector_type(4)));
typedef __bf16 bf16x8 __attribute__((ext_vector_type(8)));
typedef float f32x4 __attribute__((ext_vector_type(4)));
typedef float f32x16 __attribute__((ext_vector_type(16)));

#define MFMA16(a, b, c) __builtin_amdgcn_mfma_f32_16x16x32_bf16(a, b, c, 0, 0, 0)
#define MFMA32(a, b, c) __builtin_amdgcn_mfma_f32_32x32x16_bf16(a, b, c, 0, 0, 0)

// async global->LDS, 16 B per lane; LDS dest = uniform base + lane*16
#define GLL16(g, l)                                                      \
    __builtin_amdgcn_global_load_lds(                                    \
        (const __attribute__((address_space(1))) void*)(g),              \
        (__attribute__((address_space(3))) void*)(l), 16, 0, 0)

#define SEQ 2048
#define NHEAD 16
#define HD 64
#define HID 1024
#define QKV_LD 3072
#define VT_LD 2080  // 2048 + 32 pad: breaks 4 KB power-of-2 L2 set aliasing

// ---------------------------------------------------------------------------
// Fused prep: cast x -> bf16 (blocks 0..4095), transpose+cast w_qkv
// (4096..7167), transpose+cast w_out (7168..8191).
// ---------------------------------------------------------------------------
__global__ __launch_bounds__(256)
void prep_kernel(const float* __restrict__ x, const float* __restrict__ w_qkv,
                 const float* __restrict__ w_out, bf16_t* __restrict__ xbf,
                 bf16_t* __restrict__ wqkvT, bf16_t* __restrict__ woutT) {
    int L = blockIdx.x;
    int tid = threadIdx.x;
    if (L < 4096) {  // cast x
        int i = (L * 256 + tid) * 4;
        float4 v = *(const float4*)(x + i);
        bf16x4 o = {(bf16_t)v.x, (bf16_t)v.y, (bf16_t)v.z, (bf16_t)v.w};
        *(bf16x4*)(xbf + i) = o;
        return;
    }
    __shared__ bf16_t tile[32][33];
    const float* W;
    bf16_t* Wt;
    int N, bx, by;
    if (L < 7168) {
        int r = L - 4096;
        W = w_qkv; Wt = wqkvT; N = 3072; bx = r % 96; by = r / 96;
    } else {
        int r = L - 7168;
        W = w_out; Wt = woutT; N = 1024; bx = r % 32; by = r / 32;
    }
    int K = 1024;
    int n0 = bx * 32, k0 = by * 32;
    int tx = tid & 31, ty = tid >> 5;  // 32 x 8
#pragma unroll
    for (int i = 0; i < 4; i++)
        tile[ty + i * 8][tx] = (bf16_t)W[(size_t)(k0 + ty + i * 8) * N + n0 + tx];
    __syncthreads();
#pragma unroll
    for (int i = 0; i < 4; i++)
        Wt[(size_t)(n0 + ty + i * 8) * K + k0 + tx] = tile[tx][ty + i * 8];
}

// ---------------------------------------------------------------------------
// V transpose prepass: Vt[bh][d][s] = qkv[b][s][2048 + h*64 + d].
// ---------------------------------------------------------------------------
__global__ __launch_bounds__(256)
void vt_transpose(const bf16_t* __restrict__ qkv, bf16_t* __restrict__ Vt) {
    int s0 = blockIdx.x * 64;
    int bh = blockIdx.y;
    int b = bh >> 4, h = bh & 15;
    int tid = threadIdx.x;
    __shared__ __align__(16) bf16_t tile[64][72];

    int row = tid >> 3, c8 = (tid & 7) * 8;
#pragma unroll
    for (int it = 0; it < 2; it++) {
        int sr = row + it * 32;
        bf16x8 v = *(const bf16x8*)(qkv + ((size_t)b * SEQ + s0 + sr) * QKV_LD +
                                    2 * HID + h * HD + c8);
        *(bf16x8*)(&tile[sr][c8]) = v;
    }
    __syncthreads();
#pragma unroll
    for (int it = 0; it < 2; it++) {
        int d = row + it * 32;
        bf16x8 w;
#pragma unroll
        for (int e = 0; e < 8; e++) w[e] = tile[c8 + e][d];
        *(bf16x8*)(Vt + ((size_t)bh * HD + d) * VT_LD + s0 + c8) = w;
    }
}

// ---------------------------------------------------------------------------
// GEMM: C[M][N] = A[M][K] @ Bt[N][K]^T + bias[N].  bf16, fp32 accum, OutT out.
// 128xTN tile, BK=32, 256 thr, GLL width-16 staging into unpadded LDS.
// ---------------------------------------------------------------------------
template <typename OutT, int TN>
__global__ __launch_bounds__(256)
void gemm_bt_bias(const bf16_t* __restrict__ A, const bf16_t* __restrict__ Bt,
                  const float* __restrict__ bias, OutT* __restrict__ C,
                  int M, int N, int K) {
    constexpr int NT = TN / 32;  // acc n-tiles per wave
    __shared__ __align__(16) bf16_t As[128][32];
    __shared__ __align__(16) bf16_t Bs[TN][32];

    int m0 = blockIdx.y * 128;
    int n0 = blockIdx.x * TN;
    int tid = threadIdx.x;
    int wave = tid >> 6, lane = tid & 63;
    int quad = lane >> 4, l16 = lane & 15;
    int wm = (wave >> 1) * 64, wn = (wave & 1) * (TN / 2);

    f32x4 acc[4][NT] = {};

    const bf16_t* a_base =
        A + (size_t)(m0 + wave * 32 + (lane >> 2)) * K + (lane & 3) * 8;
    const bf16_t* b_base =
        Bt + (size_t)(n0 + wave * (TN / 4) + (lane >> 2)) * K + (lane & 3) * 8;
    bf16_t* as_base = &As[wave * 32][0];
    bf16_t* bs_base = &Bs[wave * (TN / 4)][0];

    for (int k0 = 0; k0 < K; k0 += 32) {
        GLL16(a_base + k0, as_base);
        GLL16(a_base + 16 * K + k0, as_base + 16 * 32);
        GLL16(b_base + k0, bs_base);
        if (TN == 128) GLL16(b_base + 16 * K + k0, bs_base + 16 * 32);
        __syncthreads();

        bf16x8 af[4], bfr[NT];
#pragma unroll
        for (int t = 0; t < 4; t++)
            af[t] = *(const bf16x8*)(&As[wm + t * 16 + l16][quad * 8]);
#pragma unroll
        for (int t = 0; t < NT; t++)
            bfr[t] = *(const bf16x8*)(&Bs[wn + t * 16 + l16][quad * 8]);
#pragma unroll
        for (int mt = 0; mt < 4; mt++)
#pragma unroll
            for (int nt = 0; nt < NT; nt++)
                acc[mt][nt] = MFMA16(af[mt], bfr[nt], acc[mt][nt]);
        __syncthreads();
    }

#pragma unroll
    for (int mt = 0; mt < 4; mt++) {
        int row = m0 + wm + mt * 16 + quad * 4;
#pragma unroll
        for (int nt = 0; nt < NT; nt++) {
            int col = n0 + wn + nt * 16 + l16;
            float bv = bias[col];
#pragma unroll
            for (int r = 0; r < 4; r++)
                C[(size_t)(row + r) * N + col] = (OutT)(acc[mt][nt][r] + bv);
        }
    }
}

// ---------------------------------------------------------------------------
// Attention, mask j >= i, built on mfma_f32_32x32x16_bf16 (half the LDS
// reads per FLOP vs 16x16x32 — the LDS issue pipe was ~90% saturated).
// TI=64, BJ=64, 4 waves; wave (ih=w&1, jh=w>>1):
//   QK: S^T quarter = K[j-half] . Q[i-half]^T  (A=K from LDS, B=Q in regs,
//       4 chained k-steps).  C-layout: i = lane&31 (fixed), j = r+8rq+4hi ->
//       Ps written as packed b64, row sums as per-lane scalar adds.
//   PV: O quarter (i-half ih, d-half jh) over all 64 j: A=Ps, B=Vs frags.
// 3 barriers/iter; Ps block-shared.  LDS 27.4 KB -> 5 blocks/CU capacity;
// grid 1024 (x=bh XCD-pin, y=tile LPT long-first) -> real oversubscription.
// Fragment mapping used: A/B[m|n = lane&31][k = (lane>>5)*8 + e];
// C/D: col = lane&31, row = (reg&3) + 8*(reg>>2) + 4*(lane>>5)  [m74/m101].
// ---------------------------------------------------------------------------
__global__ __launch_bounds__(256)
void attn_kernel(const bf16_t* __restrict__ qkv, const bf16_t* __restrict__ Vt,
                 bf16_t* __restrict__ attn_out) {
    int bh = blockIdx.x;        // linear%8 == bh%8 -> XCD pin
    int tile = blockIdx.y;      // y-major: tile 0 (32 iters) dispatches first
    int b = bh >> 4, h = bh & 15;

    int tid = threadIdx.x, wave = tid >> 6, lane = tid & 63;
    int l32 = lane & 31, hi = lane >> 5;
    int ih = wave & 1, jh = wave >> 1;

    const bf16_t* q_g = qkv + (size_t)b * SEQ * QKV_LD + (size_t)h * HD;
    const bf16_t* k_g = q_g + HID;
    const bf16_t* vt_g = Vt + (size_t)bh * HD * VT_LD;

    __shared__ __align__(16) bf16_t Ks[64][72];   // K tile [j][d]
    __shared__ __align__(16) bf16_t Vs[64][72];   // V^T tile [d][j]
    __shared__ __align__(16) bf16_t Ps[64][68];   // P [i][j], block-shared
    __shared__ float lsumS[4][32];                // per-wave row-sum partials

    const float QS = 0.125f * 1.44269504088896f;  // 1/sqrt(64) * log2(e)
    int i0 = tile * 64;

    // Q fragments (B-operand): Q[i = i0+ih*32+l32][k = ks*16 + hi*8 + e]
    bf16x8 qa[4];
    {
        const bf16_t* qrow = q_g + (size_t)(i0 + ih * 32 + l32) * QKV_LD + hi * 8;
#pragma unroll
        for (int ks = 0; ks < 4; ks++) {
            bf16x8 t = *(const bf16x8*)(qrow + ks * 16);
#pragma unroll
            for (int e = 0; e < 8; e++) qa[ks][e] = (bf16_t)((float)t[e] * QS);
        }
    }

    f32x16 o = {};
    float lsum = 0.0f;

    int sr = tid >> 2, sc = (tid & 3) * 8;  // staging: 64 rows x 2 b128/thread

    // preload first K/V tile into registers
    bf16x8 kr[2], vr[2];
#pragma unroll
    for (int t = 0; t < 2; t++) {
        kr[t] = *(const bf16x8*)(k_g + (size_t)(i0 + sr) * QKV_LD + sc + t * 32);
        vr[t] = *(const bf16x8*)(vt_g + (size_t)sr * VT_LD + i0 + sc + t * 32);
    }

    for (int j0 = i0; j0 < SEQ; j0 += 64) {
        __syncthreads();  // prev iteration's Ks/Vs/Ps readers done
#pragma unroll
        for (int t = 0; t < 2; t++) {
            *(bf16x8*)(&Ks[sr][sc + t * 32]) = kr[t];
            *(bf16x8*)(&Vs[sr][sc + t * 32]) = vr[t];
        }
        __syncthreads();

        // issue next tile's loads; land during compute
        if (j0 + 64 < SEQ) {
#pragma unroll
            for (int t = 0; t < 2; t++) {
                kr[t] = *(const bf16x8*)(k_g + (size_t)(j0 + 64 + sr) * QKV_LD + sc + t * 32);
                vr[t] = *(const bf16x8*)(vt_g + (size_t)sr * VT_LD + j0 + 64 + sc + t * 32);
            }
        }

        // --- QK: S^T quarter [32 j][32 i], 4 chained k-steps ---
        f32x16 st = {};
#pragma unroll
        for (int ks = 0; ks < 4; ks++) {
            bf16x8 ka = *(const bf16x8*)(&Ks[jh * 32 + l32][ks * 16 + hi * 8]);
            st = MFMA32(ka, qa[ks], st);
        }

        // --- P = exp2(st), mask (first iter only has the diagonal), pack ---
        if (j0 == i0) {
            int gi = i0 + ih * 32 + l32;
#pragma unroll
            for (int rq = 0; rq < 4; rq++) {
                bf16x4 pk;
#pragma unroll
                for (int r = 0; r < 4; r++) {
                    int gj = j0 + jh * 32 + 8 * rq + 4 * hi + r;
                    float p = (gj >= gi) ? __builtin_amdgcn_exp2f(st[rq * 4 + r]) : 0.0f;
                    lsum += p;
                    pk[r] = (bf16_t)p;
                }
                *(bf16x4*)(&Ps[ih * 32 + l32][jh * 32 + 8 * rq + 4 * hi]) = pk;
            }
        } else {
#pragma unroll
            for (int rq = 0; rq < 4; rq++) {
                bf16x4 pk;
#pragma unroll
                for (int r = 0; r < 4; r++) {
                    float p = __builtin_amdgcn_exp2f(st[rq * 4 + r]);
                    lsum += p;
                    pk[r] = (bf16_t)p;
                }
                *(bf16x4*)(&Ps[ih * 32 + l32][jh * 32 + 8 * rq + 4 * hi]) = pk;
            }
        }
        __syncthreads();  // Ps complete across waves

        // --- PV: O quarter [32 i][32 d] over 64 j (4 k-steps) ---
#pragma unroll
        for (int ks = 0; ks < 4; ks++) {
            bf16x8 pa = *(const bf16x8*)(&Ps[ih * 32 + l32][ks * 16 + hi * 8]);
            bf16x8 vb = *(const bf16x8*)(&Vs[jh * 32 + l32][ks * 16 + hi * 8]);
            o = MFMA32(pa, vb, o);
        }
    }

    // --- epilogue: combine row sums (lane pairs, then wave pairs via LDS) ---
    lsum += __shfl_xor(lsum, 32, 64);
    lsumS[wave][l32] = lsum;  // lanes l and l+32 write same value
    __syncthreads();

#pragma unroll
    for (int rq = 0; rq < 4; rq++) {
#pragma unroll
        for (int r = 0; r < 4; r++) {
            int il = 8 * rq + 4 * hi + r;                 // local i of this reg
            float rs = lsumS[ih][il] + lsumS[ih + 2][il]; // both j-halves
            int gi = i0 + ih * 32 + il;
            attn_out[(size_t)(b * SEQ + gi) * HID + h * HD + jh * 32 + l32] =
                (bf16_t)(o[rq * 4 + r] / rs);
        }
    }
}

// ---------------------------------------------------------------------------
extern "C" void kernel_launch(void* const* d_in, const int* in_sizes, int n_in,
                              void* d_out, int out_size, void* d_ws, size_t ws_size,
                              hipStream_t stream) {
    const float* x     = (const float*)d_in[0];
    const float* w_qkv = (const float*)d_in[1];
    const float* b_qkv = (const float*)d_in[2];
    const float* w_out = (const float*)d_in[3];
    const float* b_out = (const float*)d_in[4];
    float* out = (float*)d_out;

    char* ws = (char*)d_ws;
    bf16_t* xbf   = (bf16_t*)(ws);               // 8.39 MB; dead after QKV GEMM
    bf16_t* Vt    = (bf16_t*)(ws);               // 8.52 MB; overruns into wqkvT
                                                 // (dead by vt_transpose time)
    bf16_t* wqkvT = (bf16_t*)(ws + 8388608);     // 6.29 MB
    bf16_t* woutT = (bf16_t*)(ws + 14680064);    // 2.10 MB (never overwritten)
    bf16_t* qkv   = (bf16_t*)(ws + 16777216);    // 25.17 MB
    bf16_t* attn  = (bf16_t*)(ws + 41943040);    // 8.39 MB

    prep_kernel<<<8192, 256, 0, stream>>>(x, w_qkv, w_out, xbf, wqkvT, woutT);

    gemm_bt_bias<bf16_t, 128><<<dim3(3072 / 128, 4096 / 128), 256, 0, stream>>>(
        xbf, wqkvT, b_qkv, qkv, 4096, 3072, 1024);

    vt_transpose<<<dim3(SEQ / 64, 2 * NHEAD), 256, 0, stream>>>(qkv, Vt);

    attn_kernel<<<dim3(2 * NHEAD, SEQ / 64), 256, 0, stream>>>(qkv, Vt, attn);

    gemm_bt_bias<float, 64><<<dim3(1024 / 64, 4096 / 128), 256, 0, stream>>>(
        attn, woutT, b_out, out, 4096, 1024, 1024);
}